// Round 15
// baseline (424.124 us; speedup 1.0000x reference)
//
#include <hip/hip_runtime.h>

#define NBATCH 256
#define P 1024
#define Q 128
#define NS_LOOP 6   // c=||S||inf: worst w0~0.09 -> w6~0.9999; refine cleans rest

typedef _Float16 half8 __attribute__((ext_vector_type(8)));
typedef float f32x4 __attribute__((ext_vector_type(4)));
struct __attribute__((aligned(8))) Half4 { _Float16 x, y, z, w; };   // 8 bytes

// raw workgroup barrier without HIP's implicit vmcnt(0) drain.
__device__ __forceinline__ void barrier_lds_only() {
    asm volatile("s_waitcnt lgkmcnt(0)" ::: "memory");
    __builtin_amdgcn_s_barrier();
    asm volatile("" ::: "memory");
}
__device__ __forceinline__ void barrier_plain() {
    asm volatile("" ::: "memory");
    __builtin_amdgcn_s_barrier();
    asm volatile("" ::: "memory");
}

// ---- swizzled fp16 machinery for ns/apply (counter-clean since r6) ----
__device__ __forceinline__ half8 frag_ld(const Half4* S, int rowbase, int slotbase, int lane) {
    const int r = rowbase + (lane & 15);
    const int g = (lane >> 4);
    const int rx = r & 15;
    const Half4 h1 = S[r * 32 + ((slotbase + g) ^ rx)];
    const Half4 h2 = S[r * 32 + ((slotbase + g + 4) ^ rx)];
    half8 v;
    v[0] = h1.x; v[1] = h1.y; v[2] = h1.z; v[3] = h1.w;
    v[4] = h2.x; v[5] = h2.y; v[6] = h2.z; v[7] = h2.w;
    return v;
}

__device__ __forceinline__ int cpos(int RB, int CB, int lane) {
    const int r = CB + (lane & 15);
    const int s = (RB >> 2) + (lane >> 4);
    return r * 32 + (s ^ (r & 15));
}

__device__ __forceinline__ f32x4 cread(const Half4* S, int p) {
    const Half4 h = S[p];
    f32x4 v;
    v[0] = (float)h.x; v[1] = (float)h.y; v[2] = (float)h.z; v[3] = (float)h.w;
    return v;
}

__device__ __forceinline__ void cwrite(Half4* S, int p, f32x4 v) {
    Half4 h;
    h.x = (_Float16)v[0]; h.y = (_Float16)v[1]; h.z = (_Float16)v[2]; h.w = (_Float16)v[3];
    S[p] = h;
}

__device__ __forceinline__ void cwrite_hl(Half4* Sh, Half4* Sl, int p, f32x4 v) {
    Half4 h, l;
    h.x = (_Float16)v[0]; h.y = (_Float16)v[1]; h.z = (_Float16)v[2]; h.w = (_Float16)v[3];
    l.x = (_Float16)(v[0] - (float)h.x);
    l.y = (_Float16)(v[1] - (float)h.y);
    l.z = (_Float16)(v[2] - (float)h.z);
    l.w = (_Float16)(v[3] - (float)h.w);
    Sh[p] = h; Sl[p] = l;
}

// ---- pitch-38 transposed fragment read for gram (r13 logic, wider pitch:
// r-stride 19 banks, coprime to 32 -> conflict-free reads AND 2-way-free
// Half4 writes). Logical layout identical to r11-13 -> bit-identical gram.
__device__ __forceinline__ half8 frag_ld38(const _Float16* S, int rowbase, int lane) {
    const int r = rowbase + (lane & 15);
    const int g = lane >> 4;
    const Half4 h1 = *(const Half4*)(S + r * 38 + 4 * g);
    const Half4 h2 = *(const Half4*)(S + r * 38 + 16 + 4 * g);
    half8 v;
    v[0] = h1.x; v[1] = h1.y; v[2] = h1.z; v[3] = h1.w;
    v[4] = h2.x; v[5] = h2.y; v[6] = h2.z; v[7] = h2.w;
    return v;
}

// ---- gram helpers ----
// Thread (u = tid&3, q4 = (tid>>2)&31, pb = 4*(tid>>7)): loads rows
// pb+u (+16t) at float4-col q4 -> quad shfl-transpose -> Half4 p-major writes.
__device__ __forceinline__ void gload4(const float* __restrict__ xb,
    const float* __restrict__ gb, float lr, int pbase, int prow0, int q4, float4* tv)
{
#pragma unroll
    for (int t = 0; t < 2; ++t) {
        const int p = prow0 + t * 16;
        const float4 xv = ((const float4*)(xb + (size_t)(pbase + p) * Q))[q4];
        const float4 gv = ((const float4*)(gb + (size_t)(pbase + p) * Q))[q4];
        tv[t] = make_float4(xv.x - lr * gv.x, xv.y - lr * gv.y,
                            xv.z - lr * gv.z, xv.w - lr * gv.w);
    }
}

__device__ __forceinline__ void gstore4t(_Float16* sHi, _Float16* sLo,
    int u, int q4, int pb, const float4* tv,
    _Float16* __restrict__ th, int pbase, int prow0)
{
    if (th) {   // tempH: q-major hi-cast, pre-transpose (coalesced Half4)
#pragma unroll
        for (int t = 0; t < 2; ++t) {
            Half4 hh;
            hh.x = (_Float16)tv[t].x; hh.y = (_Float16)tv[t].y;
            hh.z = (_Float16)tv[t].z; hh.w = (_Float16)tv[t].w;
            *(Half4*)(th + (size_t)(pbase + prow0 + 16 * t) * Q + 4 * q4) = hh;
        }
    }
#pragma unroll
    for (int t = 0; t < 2; ++t) {
        float E[4] = {tv[t].x, tv[t].y, tv[t].z, tv[t].w};
        // quad 4x4 transpose: round 1 (lanes^1, element bit0)
        {
            float a0 = (u & 1) ? E[0] : E[1];
            float a1 = (u & 1) ? E[2] : E[3];
            const float r0 = __shfl_xor(a0, 1);
            const float r1 = __shfl_xor(a1, 1);
            if (u & 1) { E[0] = r0; E[2] = r1; } else { E[1] = r0; E[3] = r1; }
        }
        // round 2 (lanes^2, element bit1)
        {
            float a0 = (u & 2) ? E[0] : E[2];
            float a1 = (u & 2) ? E[1] : E[3];
            const float r0 = __shfl_xor(a0, 2);
            const float r1 = __shfl_xor(a1, 2);
            if (u & 2) { E[0] = r0; E[1] = r1; } else { E[2] = r0; E[3] = r1; }
        }
        // now E[i] = T[pb+i (+16t)][4*q4+u]
        const int qq = 4 * q4 + u;
        const int pr = pb + 16 * t;
        Half4 hh, ll;
        _Float16* hp = (_Float16*)&hh;
        _Float16* lp = (_Float16*)&ll;
#pragma unroll
        for (int i = 0; i < 4; ++i) {
            hp[i] = (_Float16)E[i];
            lp[i] = (_Float16)(E[i] - (float)hp[i]);
        }
        *(Half4*)(sHi + qq * 38 + pr) = hh;
        *(Half4*)(sLo + qq * 38 + pr) = ll;
    }
}

__device__ __forceinline__ void gram_mfma(const _Float16* sHi, const _Float16* sLo,
    int RB, int lane, f32x4* acc)
{
    const half8 ahi = frag_ld38(sHi, RB, lane);
    const half8 alo = frag_ld38(sLo, RB, lane);
#pragma unroll
    for (int fj = 0; fj < 8; ++fj) {
        const half8 bhi = frag_ld38(sHi, fj * 16, lane);
        const half8 blo = frag_ld38(sLo, fj * 16, lane);
        acc[fj] = __builtin_amdgcn_mfma_f32_16x16x32_f16(ahi, bhi, acc[fj], 0, 0, 0);
        acc[fj] = __builtin_amdgcn_mfma_f32_16x16x32_f16(ahi, blo, acc[fj], 0, 0, 0);
        acc[fj] = __builtin_amdgcn_mfma_f32_16x16x32_f16(alo, bhi, acc[fj], 0, 0, 0);
    }
}

// ---------------------------------------------------------------------------
// Kernel 1: partial gram, fp16 MFMA hi/lo. r15: float4 global loads (r14)
// AND Half4 LDS writes (r13) via in-register quad shfl-transpose -- both
// memory sides wide + conflict-free (r13/r14 each had one side scalar).
// ---------------------------------------------------------------------------
__global__ __launch_bounds__(512) void gram_kernel(
    const float* __restrict__ X, const float* __restrict__ G,
    const float* __restrict__ lrp, float* __restrict__ gpart, int npart,
    _Float16* __restrict__ tempH)
{
    __shared__ _Float16 sHi[128 * 38];   // 9728 B
    __shared__ _Float16 sLo[128 * 38];

    const int n = blockIdx.x / npart;
    const int part = blockIdx.x - n * npart;
    const int rows = P / npart;
    const float lr = *lrp;
    const float* xb = X + (size_t)n * P * Q;
    const float* gb = G + (size_t)n * P * Q;
    _Float16* th = tempH ? tempH + (size_t)n * P * Q : (_Float16*)0;

    const int tid = threadIdx.x;
    const int lane = tid & 63;
    const int wid = tid >> 6;
    const int RB = wid * 16;
    const int u  = tid & 3;
    const int q4 = (tid >> 2) & 31;
    const int pb = (tid >> 7) * 4;
    const int prow0 = pb + u;

    const f32x4 zero4 = {0.0f, 0.0f, 0.0f, 0.0f};
    f32x4 acc[8];
#pragma unroll
    for (int fj = 0; fj < 8; ++fj) acc[fj] = zero4;

    const int pstart = part * rows;
    const int nch = rows / 32;       // even

    float4 tA[2], tB[2];
    gload4(xb, gb, lr, pstart, prow0, q4, tA);

    for (int c = 0; c < nch; c += 2) {
        barrier_plain();
        gstore4t(sHi, sLo, u, q4, pb, tA, th, pstart + c * 32, prow0);
        if (c + 1 < nch) gload4(xb, gb, lr, pstart + (c + 1) * 32, prow0, q4, tB);
        barrier_lds_only();
        gram_mfma(sHi, sLo, RB, lane, acc);

        barrier_plain();
        gstore4t(sHi, sLo, u, q4, pb, tB, th, pstart + (c + 1) * 32, prow0);
        if (c + 2 < nch) gload4(xb, gb, lr, pstart + (c + 2) * 32, prow0, q4, tA);
        barrier_lds_only();
        gram_mfma(sHi, sLo, RB, lane, acc);
    }

    float* gm = gpart + ((size_t)n * npart + part) * Q * Q;
    const int m0 = (lane >> 4) * 4;
    const int nn = lane & 15;
#pragma unroll
    for (int fj = 0; fj < 8; ++fj) {
#pragma unroll
        for (int j = 0; j < 4; ++j) {
            gm[(size_t)(RB + m0 + j) * Q + fj * 16 + nn] = acc[fj][j];
        }
    }
}

// ---------------------------------------------------------------------------
// Kernel 2: Newton-Schulz (fp16 MFMA) + fused fp32-grade refinement.
// r15: c = ||S||_inf (Gershgorin >= lambda_max, ~3x tighter than Frobenius)
// -> 6 iterations suffice (worst w0~0.09 -> w6~0.9999; refine cleans rest).
// ---------------------------------------------------------------------------
__global__ __launch_bounds__(512) void ns_kernel(
    const float* __restrict__ gpart, int npart, float* __restrict__ Zg)
{
    __shared__ __align__(16) unsigned char pool[163840];
    Half4* bufA = (Half4*)pool;               // W ping / r-hi
    Half4* bufB = (Half4*)(pool + 32768);     // W pong / r-lo
    Half4* sZh  = (Half4*)(pool + 65536);     // Z iterate
    Half4* bufC = (Half4*)(pool + 98304);     // A-hi / u-hi
    Half4* bufD = (Half4*)(pool + 131072);    // A-lo / u-lo
    float* sRow = (float*)pool;               // 128 row-sums, aliases bufA head

    const int n = blockIdx.x;
    const int tid = threadIdx.x;
    const float* gp = gpart + (size_t)n * npart * Q * Q;

    // ---- load + sum partial grams; row abs-sums for ||S||_inf ----
    float4 gv[8];
    float rsum[8];
#pragma unroll
    for (int t = 0; t < 8; ++t) {
        const int idx = tid + t * 512;
        float4 v = ((const float4*)gp)[idx];
        for (int pp = 1; pp < npart; ++pp) {
            const float4 w = ((const float4*)(gp + (size_t)pp * Q * Q))[idx];
            v.x += w.x; v.y += w.y; v.z += w.z; v.w += w.w;
        }
        gv[t] = v;
        rsum[t] = fabsf(v.x) + fabsf(v.y) + fabsf(v.z) + fabsf(v.w);
    }
    // row = (tid>>5)+16t, its 32 pieces live in lanes of one 32-lane group
#pragma unroll
    for (int t = 0; t < 8; ++t) {
#pragma unroll
        for (int off = 16; off > 0; off >>= 1)
            rsum[t] += __shfl_xor(rsum[t], off);
    }
    if ((tid & 31) == 0) {
#pragma unroll
        for (int t = 0; t < 8; ++t)
            sRow[(tid >> 5) + 16 * t] = rsum[t];
    }
    __syncthreads();
    float cmax = 0.0f;
#pragma unroll
    for (int i = 0; i < 4; ++i)
        cmax = fmaxf(cmax, sRow[(tid & 31) + 32 * i]);
#pragma unroll
    for (int off = 16; off > 0; off >>= 1)
        cmax = fmaxf(cmax, __shfl_xor(cmax, off));
    __syncthreads();   // sRow reads done before bufA init overwrites alias
    const float c = cmax;
    const float rc = 1.0f / c;
    const float rs = 1.0f / sqrtf(c);

    // ---- init: A = S*rc hi/lo -> bufC/bufD; W0 = A-hi; Z0 = 1.5I - 0.5A ----
#pragma unroll
    for (int t = 0; t < 8; ++t) {
        const int idx = tid + t * 512;
        const int row = idx >> 5, c4 = idx & 31;
        const int slot = row * 32 + (c4 ^ (row & 15));
        float wv[4], zv[4];
        wv[0] = gv[t].x * rc; wv[1] = gv[t].y * rc;
        wv[2] = gv[t].z * rc; wv[3] = gv[t].w * rc;
        Half4 wh, wl, zh;
        _Float16* whp = (_Float16*)&wh;
        _Float16* wlp = (_Float16*)&wl;
        _Float16* zhp = (_Float16*)&zh;
#pragma unroll
        for (int j = 0; j < 4; ++j) {
            const _Float16 h = (_Float16)wv[j];
            whp[j] = h;
            wlp[j] = (_Float16)(wv[j] - (float)h);
            zv[j] = -0.5f * wv[j] + (((row >> 2) == c4 && (row & 3) == j) ? 1.5f : 0.0f);
            zhp[j] = (_Float16)zv[j];
        }
        bufA[slot] = wh;
        bufC[slot] = wh;
        bufD[slot] = wl;
        sZh[slot] = zh;
    }
    __syncthreads();

    const int lane = tid & 63;
    const int wid = tid >> 6;
    const int RB = wid * 16;
    const f32x4 zero4 = {0.0f, 0.0f, 0.0f, 0.0f};
    Half4* cur = bufA;
    Half4* scr = bufB;

    for (int it = 0; it < NS_LOOP; ++it) {
        f32x4 a1[8];
#pragma unroll
        for (int fj = 0; fj < 8; ++fj) a1[fj] = zero4;
#pragma unroll
        for (int kb = 0; kb < 4; ++kb) {
            const half8 af = frag_ld(cur, RB, kb * 8, lane);
#pragma unroll
            for (int fj = 0; fj < 8; ++fj) {
                const half8 bf = frag_ld(cur, fj * 16, kb * 8, lane);
                a1[fj] = __builtin_amdgcn_mfma_f32_16x16x32_f16(af, bf, a1[fj], 0, 0, 0);
            }
        }
#pragma unroll
        for (int fj = 0; fj < 8; ++fj) {
            const int p = cpos(RB, fj * 16, lane);
            cwrite(scr, p, 1.5f * cread(cur, p) - 0.5f * a1[fj]);
        }
        __syncthreads();

        f32x4 a2[8];
#pragma unroll
        for (int fj = 0; fj < 8; ++fj) a2[fj] = zero4;
#pragma unroll
        for (int kb = 0; kb < 4; ++kb) {
            const half8 af = frag_ld(scr, RB, kb * 8, lane);
#pragma unroll
            for (int fj = 0; fj < 8; ++fj) {
                const half8 bf = frag_ld(cur, fj * 16, kb * 8, lane);
                a2[fj] = __builtin_amdgcn_mfma_f32_16x16x32_f16(af, bf, a2[fj], 0, 0, 0);
            }
        }
        f32x4 wn[8];
#pragma unroll
        for (int fj = 0; fj < 8; ++fj) {
            const int p = cpos(RB, fj * 16, lane);
            wn[fj] = 1.5f * cread(scr, p) - 0.5f * a2[fj];
        }
        __syncthreads();
#pragma unroll
        for (int fj = 0; fj < 8; ++fj)
            cwrite(scr, cpos(RB, fj * 16, lane), wn[fj]);
        __syncthreads();

        f32x4 a3[8];
#pragma unroll
        for (int fj = 0; fj < 8; ++fj) a3[fj] = zero4;
#pragma unroll
        for (int kb = 0; kb < 4; ++kb) {
            const half8 af = frag_ld(scr, RB, kb * 8, lane);
#pragma unroll
            for (int fj = 0; fj < 8; ++fj) {
                const half8 bf = frag_ld(sZh, fj * 16, kb * 8, lane);
                a3[fj] = __builtin_amdgcn_mfma_f32_16x16x32_f16(af, bf, a3[fj], 0, 0, 0);
            }
        }
        f32x4 zn[8];
#pragma unroll
        for (int fj = 0; fj < 8; ++fj) {
            const int p = cpos(RB, fj * 16, lane);
            zn[fj] = 1.5f * cread(sZh, p) - 0.5f * a3[fj];
        }
        __syncthreads();
#pragma unroll
        for (int fj = 0; fj < 8; ++fj)
            cwrite(sZh, cpos(RB, fj * 16, lane), zn[fj]);
        __syncthreads();

        Half4* tmp = cur; cur = scr; scr = tmp;
    }

    // symmetrize z exactly
    {
        _Float16* zp = (_Float16*)sZh;
        for (int k = tid; k < Q * Q; k += 512) {
            const int r = k >> 7, cc = k & 127;
            if (r < cc) {
                const int i1 = (r * 32 + ((cc >> 2) ^ (r & 15))) * 4 + (cc & 3);
                const int i2 = (cc * 32 + ((r >> 2) ^ (cc & 15))) * 4 + (r & 3);
                const _Float16 av = (_Float16)(0.5f * ((float)zp[i1] + (float)zp[i2]));
                zp[i1] = av; zp[i2] = av;
            }
        }
    }
    __syncthreads();

    // racc = A*z -> cpos store = rows of (z*A)
    f32x4 racc[8];
#pragma unroll
    for (int fj = 0; fj < 8; ++fj) racc[fj] = zero4;
#pragma unroll
    for (int kb = 0; kb < 4; ++kb) {
        const half8 ah = frag_ld(bufC, RB, kb * 8, lane);
        const half8 al = frag_ld(bufD, RB, kb * 8, lane);
#pragma unroll
        for (int fj = 0; fj < 8; ++fj) {
            const half8 bz = frag_ld(sZh, fj * 16, kb * 8, lane);
            racc[fj] = __builtin_amdgcn_mfma_f32_16x16x32_f16(ah, bz, racc[fj], 0, 0, 0);
            racc[fj] = __builtin_amdgcn_mfma_f32_16x16x32_f16(al, bz, racc[fj], 0, 0, 0);
        }
    }
#pragma unroll
    for (int fj = 0; fj < 8; ++fj)
        cwrite_hl(bufA, bufB, cpos(RB, fj * 16, lane), racc[fj]);
    __syncthreads();

    // uacc = z*z -> bufC/bufD hi/lo
    f32x4 uacc[8];
#pragma unroll
    for (int fj = 0; fj < 8; ++fj) uacc[fj] = zero4;
#pragma unroll
    for (int kb = 0; kb < 4; ++kb) {
        const half8 az = frag_ld(sZh, RB, kb * 8, lane);
#pragma unroll
        for (int fj = 0; fj < 8; ++fj) {
            const half8 bz = frag_ld(sZh, fj * 16, kb * 8, lane);
            uacc[fj] = __builtin_amdgcn_mfma_f32_16x16x32_f16(az, bz, uacc[fj], 0, 0, 0);
        }
    }
#pragma unroll
    for (int fj = 0; fj < 8; ++fj)
        cwrite_hl(bufC, bufD, cpos(RB, fj * 16, lane), uacc[fj]);
    __syncthreads();

    // d = (z*A)*u ; Z_ref = rs*(1.5 z - 0.5 d)
    f32x4 dacc[8];
#pragma unroll
    for (int fj = 0; fj < 8; ++fj) dacc[fj] = zero4;
#pragma unroll
    for (int kb = 0; kb < 4; ++kb) {
        const half8 rh = frag_ld(bufA, RB, kb * 8, lane);
        const half8 rl = frag_ld(bufB, RB, kb * 8, lane);
#pragma unroll
        for (int fj = 0; fj < 8; ++fj) {
            const half8 uh = frag_ld(bufC, fj * 16, kb * 8, lane);
            const half8 ul = frag_ld(bufD, fj * 16, kb * 8, lane);
            dacc[fj] = __builtin_amdgcn_mfma_f32_16x16x32_f16(rh, uh, dacc[fj], 0, 0, 0);
            dacc[fj] = __builtin_amdgcn_mfma_f32_16x16x32_f16(rh, ul, dacc[fj], 0, 0, 0);
            dacc[fj] = __builtin_amdgcn_mfma_f32_16x16x32_f16(rl, uh, dacc[fj], 0, 0, 0);
        }
    }

    float* zo = Zg + (size_t)n * Q * Q;
    const int m0 = (lane >> 4) * 4;
    const int nn = lane & 15;
#pragma unroll
    for (int fj = 0; fj < 8; ++fj) {
        const f32x4 zq = cread(sZh, cpos(RB, fj * 16, lane));
#pragma unroll
        for (int j = 0; j < 4; ++j) {
            zo[(size_t)(RB + m0 + j) * Q + fj * 16 + nn] =
                rs * (1.5f * zq[j] - 0.5f * dacc[fj][j]);
        }
    }
}

// ---------------------------------------------------------------------------
// Kernel 3: out[n] = temp[n] @ Zg[n], fp16 MFMA; tempH fast path (r13).
// ---------------------------------------------------------------------------
__global__ __launch_bounds__(512) void apply_kernel(
    const float* __restrict__ X, const float* __restrict__ G,
    const float* __restrict__ lrp, const float* __restrict__ Zg,
    const _Float16* __restrict__ tempH, int use_th,
    float* __restrict__ out)
{
    __shared__ __align__(16) unsigned char pool[65536];
    Half4* sTh = (Half4*)pool;
    Half4* sZh = (Half4*)(pool + 32768);

    const int n = blockIdx.x >> 3;
    const int p0 = (blockIdx.x & 7) * 128;
    const int tid = threadIdx.x;
    const float* zb = Zg + (size_t)n * Q * Q;
    float* ob = out + (size_t)n * P * Q + (size_t)p0 * Q;

#pragma unroll
    for (int t = 0; t < 8; ++t) {
        const int idx = tid + t * 512;
        const int row = idx >> 5, c4 = idx & 31;
        const float4 v = ((const float4*)zb)[idx];
        Half4 h;
        h.x = (_Float16)v.x; h.y = (_Float16)v.y;
        h.z = (_Float16)v.z; h.w = (_Float16)v.w;
        sZh[row * 32 + (c4 ^ (row & 15))] = h;
    }

    if (use_th) {
        const _Float16* tb = tempH + ((size_t)n * P + p0) * Q;
#pragma unroll
        for (int t = 0; t < 4; ++t) {
            const int idx = tid + t * 512;
            const int row = idx >> 4, hg = idx & 15;
            const half8 hv = ((const half8*)tb)[idx];
            Half4 h1, h2;
            h1.x = hv[0]; h1.y = hv[1]; h1.z = hv[2]; h1.w = hv[3];
            h2.x = hv[4]; h2.y = hv[5]; h2.z = hv[6]; h2.w = hv[7];
            const int rx = row & 15;
            sTh[row * 32 + ((hg * 2) ^ rx)] = h1;
            sTh[row * 32 + ((hg * 2 + 1) ^ rx)] = h2;
        }
    } else {
        const float lr = *lrp;
        const float* xb = X + (size_t)n * P * Q + (size_t)p0 * Q;
        const float* gb = G + (size_t)n * P * Q + (size_t)p0 * Q;
#pragma unroll
        for (int t = 0; t < 8; ++t) {
            const int idx = tid + t * 512;
            const int row = idx >> 5, c4 = idx & 31;
            const float4 xv = ((const float4*)xb)[idx];
            const float4 gv = ((const float4*)gb)[idx];
            Half4 h;
            h.x = (_Float16)(xv.x - lr * gv.x);
            h.y = (_Float16)(xv.y - lr * gv.y);
            h.z = (_Float16)(xv.z - lr * gv.z);
            h.w = (_Float16)(xv.w - lr * gv.w);
            sTh[row * 32 + (c4 ^ (row & 15))] = h;
        }
    }
    __syncthreads();

    const int lane = tid & 63;
    const int wid = tid >> 6;
    const int RB = wid * 16;
    const f32x4 zero4 = {0.0f, 0.0f, 0.0f, 0.0f};

    f32x4 a[8];
#pragma unroll
    for (int fj = 0; fj < 8; ++fj) a[fj] = zero4;
#pragma unroll
    for (int kb = 0; kb < 4; ++kb) {
        const half8 af = frag_ld(sTh, RB, kb * 8, lane);
#pragma unroll
        for (int fj = 0; fj < 8; ++fj) {
            const half8 bf = frag_ld(sZh, fj * 16, kb * 8, lane);
            a[fj] = __builtin_amdgcn_mfma_f32_16x16x32_f16(af, bf, a[fj], 0, 0, 0);
        }
    }

    const int m0 = (lane >> 4) * 4;
    const int nn = lane & 15;
#pragma unroll
    for (int fj = 0; fj < 8; ++fj) {
#pragma unroll
        for (int j = 0; j < 4; ++j) {
            ob[(size_t)(RB + m0 + j) * Q + fj * 16 + nn] = a[fj][j];
        }
    }
}

extern "C" void kernel_launch(void* const* d_in, const int* in_sizes, int n_in,
                              void* d_out, int out_size, void* d_ws, size_t ws_size,
                              hipStream_t stream) {
    const float* X  = (const float*)d_in[0];
    const float* G  = (const float*)d_in[1];
    const float* lr = (const float*)d_in[2];
    float* outp = (float*)d_out;

    const size_t QQ = (size_t)Q * Q;
    const size_t mat = (size_t)NBATCH * QQ;
    const size_t thHalves = (size_t)NBATCH * P * Q;

    const int npart_want = 4;
    const size_t need_np = (1 + npart_want) * mat * sizeof(float);
    const int npart = (ws_size >= need_np) ? npart_want : 1;
    const size_t need_th = need_np + thHalves * sizeof(_Float16);
    const int use_th = (npart == npart_want && ws_size >= need_th) ? 1 : 0;

    float* Zg    = (float*)d_ws;
    float* gpart = Zg + mat;
    _Float16* tempH = use_th ? (_Float16*)(gpart + (size_t)npart * mat) : (_Float16*)0;

    gram_kernel<<<NBATCH * npart, 512, 0, stream>>>(X, G, lr, gpart, npart, tempH);
    ns_kernel<<<NBATCH, 512, 0, stream>>>(gpart, npart, Zg);
    apply_kernel<<<NBATCH * 8, 512, 0, stream>>>(X, G, lr, Zg, tempH, use_th, outp);
}

// Round 16
// 211.133 us; speedup vs baseline: 2.0088x; 2.0088x over previous
//
#include <hip/hip_runtime.h>

#define NBATCH 256
#define P 1024
#define Q 128
#define NS_LOOP 6   // c=||S||inf (Gershgorin): validated r15, absmax unchanged

typedef _Float16 half8 __attribute__((ext_vector_type(8)));
typedef float f32x4 __attribute__((ext_vector_type(4)));
struct __attribute__((aligned(8))) Half4 { _Float16 x, y, z, w; };   // 8 bytes

// raw workgroup barrier without HIP's implicit vmcnt(0) drain.
__device__ __forceinline__ void barrier_lds_only() {
    asm volatile("s_waitcnt lgkmcnt(0)" ::: "memory");
    __builtin_amdgcn_s_barrier();
    asm volatile("" ::: "memory");
}
__device__ __forceinline__ void barrier_plain() {
    asm volatile("" ::: "memory");
    __builtin_amdgcn_s_barrier();
    asm volatile("" ::: "memory");
}

// ---- swizzled fp16 machinery for ns/apply (counter-clean since r6) ----
__device__ __forceinline__ half8 frag_ld(const Half4* S, int rowbase, int slotbase, int lane) {
    const int r = rowbase + (lane & 15);
    const int g = (lane >> 4);
    const int rx = r & 15;
    const Half4 h1 = S[r * 32 + ((slotbase + g) ^ rx)];
    const Half4 h2 = S[r * 32 + ((slotbase + g + 4) ^ rx)];
    half8 v;
    v[0] = h1.x; v[1] = h1.y; v[2] = h1.z; v[3] = h1.w;
    v[4] = h2.x; v[5] = h2.y; v[6] = h2.z; v[7] = h2.w;
    return v;
}

__device__ __forceinline__ int cpos(int RB, int CB, int lane) {
    const int r = CB + (lane & 15);
    const int s = (RB >> 2) + (lane >> 4);
    return r * 32 + (s ^ (r & 15));
}

__device__ __forceinline__ f32x4 cread(const Half4* S, int p) {
    const Half4 h = S[p];
    f32x4 v;
    v[0] = (float)h.x; v[1] = (float)h.y; v[2] = (float)h.z; v[3] = (float)h.w;
    return v;
}

__device__ __forceinline__ void cwrite(Half4* S, int p, f32x4 v) {
    Half4 h;
    h.x = (_Float16)v[0]; h.y = (_Float16)v[1]; h.z = (_Float16)v[2]; h.w = (_Float16)v[3];
    S[p] = h;
}

__device__ __forceinline__ void cwrite_hl(Half4* Sh, Half4* Sl, int p, f32x4 v) {
    Half4 h, l;
    h.x = (_Float16)v[0]; h.y = (_Float16)v[1]; h.z = (_Float16)v[2]; h.w = (_Float16)v[3];
    l.x = (_Float16)(v[0] - (float)h.x);
    l.y = (_Float16)(v[1] - (float)h.y);
    l.z = (_Float16)(v[2] - (float)h.z);
    l.w = (_Float16)(v[3] - (float)h.w);
    Sh[p] = h; Sl[p] = l;
}

// ---- pitch-36 transposed fragment read for gram, with p-group XOR swizzle
// (r14 layout: write p' = p ^ ((q4&7)<<2); read group g ^ ((r>>2)&7)).
__device__ __forceinline__ half8 frag_ld36s(const _Float16* S, int rowbase, int lane) {
    const int r = rowbase + (lane & 15);
    const int g = lane >> 4;
    const int xg = (r >> 2) & 7;
    const Half4 h1 = *(const Half4*)(S + r * 36 + 4 * (g ^ xg));
    const Half4 h2 = *(const Half4*)(S + r * 36 + 4 * ((g + 4) ^ xg));
    half8 v;
    v[0] = h1.x; v[1] = h1.y; v[2] = h1.z; v[3] = h1.w;
    v[4] = h2.x; v[5] = h2.y; v[6] = h2.z; v[7] = h2.w;
    return v;
}

// ---- gram helpers (r14, best measured) ----
__device__ __forceinline__ void gload4(const float* __restrict__ xb,
    const float* __restrict__ gb, float lr, int pbase, int pa, int q4, float4* tv)
{
#pragma unroll
    for (int t = 0; t < 2; ++t) {
        const int p = pa + t * 16;
        const float4 xv = ((const float4*)(xb + (size_t)(pbase + p) * Q))[q4];
        const float4 gv = ((const float4*)(gb + (size_t)(pbase + p) * Q))[q4];
        tv[t] = make_float4(xv.x - lr * gv.x, xv.y - lr * gv.y,
                            xv.z - lr * gv.z, xv.w - lr * gv.w);
    }
}

__device__ __forceinline__ void gstore4(_Float16* sHi, _Float16* sLo,
    int pa, int q4, const float4* tv, _Float16* __restrict__ th, int pbase)
{
    const int x = (q4 & 7) << 2;
#pragma unroll
    for (int t = 0; t < 2; ++t) {
        const int p = pa + t * 16;
        const float v[4] = {tv[t].x, tv[t].y, tv[t].z, tv[t].w};
        Half4 hh;
        _Float16* hp = (_Float16*)&hh;
        _Float16 lo[4];
#pragma unroll
        for (int i = 0; i < 4; ++i) {
            hp[i] = (_Float16)v[i];
            lo[i] = (_Float16)(v[i] - (float)hp[i]);
        }
        if (th) *(Half4*)(th + (size_t)(pbase + p) * Q + 4 * q4) = hh;  // 8B store
        const int pp = p ^ x;
#pragma unroll
        for (int i = 0; i < 4; ++i) {
            const int q = 4 * q4 + i;
            sHi[q * 36 + pp] = hp[i];
            sLo[q * 36 + pp] = lo[i];
        }
    }
}

__device__ __forceinline__ void gram_mfma(const _Float16* sHi, const _Float16* sLo,
    int RB, int lane, f32x4* acc)
{
    const half8 ahi = frag_ld36s(sHi, RB, lane);
    const half8 alo = frag_ld36s(sLo, RB, lane);
#pragma unroll
    for (int fj = 0; fj < 8; ++fj) {
        const half8 bhi = frag_ld36s(sHi, fj * 16, lane);
        const half8 blo = frag_ld36s(sLo, fj * 16, lane);
        acc[fj] = __builtin_amdgcn_mfma_f32_16x16x32_f16(ahi, bhi, acc[fj], 0, 0, 0);
        acc[fj] = __builtin_amdgcn_mfma_f32_16x16x32_f16(ahi, blo, acc[fj], 0, 0, 0);
        acc[fj] = __builtin_amdgcn_mfma_f32_16x16x32_f16(alo, bhi, acc[fj], 0, 0, 0);
    }
}

// ---------------------------------------------------------------------------
// Kernel 1: partial gram (r14 exact — best measured at ~120us).
// r15's shfl-transpose regressed 3x (divergent branches around shfl).
// ---------------------------------------------------------------------------
__global__ __launch_bounds__(512) void gram_kernel(
    const float* __restrict__ X, const float* __restrict__ G,
    const float* __restrict__ lrp, float* __restrict__ gpart, int npart,
    _Float16* __restrict__ tempH)
{
    __shared__ _Float16 sHi[128 * 36];
    __shared__ _Float16 sLo[128 * 36];

    const int n = blockIdx.x / npart;
    const int part = blockIdx.x - n * npart;
    const int rows = P / npart;
    const float lr = *lrp;
    const float* xb = X + (size_t)n * P * Q;
    const float* gb = G + (size_t)n * P * Q;
    _Float16* th = tempH ? tempH + (size_t)n * P * Q : (_Float16*)0;

    const int tid = threadIdx.x;
    const int lane = tid & 63;
    const int wid = tid >> 6;
    const int RB = wid * 16;
    const int q4 = tid & 31;
    const int pa = tid >> 5;

    const f32x4 zero4 = {0.0f, 0.0f, 0.0f, 0.0f};
    f32x4 acc[8];
#pragma unroll
    for (int fj = 0; fj < 8; ++fj) acc[fj] = zero4;

    const int pstart = part * rows;
    const int nch = rows / 32;

    float4 tA[2], tB[2];
    gload4(xb, gb, lr, pstart, pa, q4, tA);

    for (int c = 0; c < nch; c += 2) {
        barrier_plain();
        gstore4(sHi, sLo, pa, q4, tA, th, pstart + c * 32);
        if (c + 1 < nch) gload4(xb, gb, lr, pstart + (c + 1) * 32, pa, q4, tB);
        barrier_lds_only();
        gram_mfma(sHi, sLo, RB, lane, acc);

        barrier_plain();
        gstore4(sHi, sLo, pa, q4, tB, th, pstart + (c + 1) * 32);
        if (c + 2 < nch) gload4(xb, gb, lr, pstart + (c + 2) * 32, pa, q4, tA);
        barrier_lds_only();
        gram_mfma(sHi, sLo, RB, lane, acc);
    }

    float* gm = gpart + ((size_t)n * npart + part) * Q * Q;
    const int m0 = (lane >> 4) * 4;
    const int nn = lane & 15;
#pragma unroll
    for (int fj = 0; fj < 8; ++fj) {
#pragma unroll
        for (int j = 0; j < 4; ++j) {
            gm[(size_t)(RB + m0 + j) * Q + fj * 16 + nn] = acc[fj][j];
        }
    }
}

// ---------------------------------------------------------------------------
// Kernel 2: Newton-Schulz (fp16 MFMA) + fused fp32-grade refinement.
// c = ||S||_inf -> 6 iterations (validated r15: absmax bit-identical).
// ---------------------------------------------------------------------------
__global__ __launch_bounds__(512) void ns_kernel(
    const float* __restrict__ gpart, int npart, float* __restrict__ Zg)
{
    __shared__ __align__(16) unsigned char pool[163840];
    Half4* bufA = (Half4*)pool;               // W ping / r-hi
    Half4* bufB = (Half4*)(pool + 32768);     // W pong / r-lo
    Half4* sZh  = (Half4*)(pool + 65536);     // Z iterate
    Half4* bufC = (Half4*)(pool + 98304);     // A-hi / u-hi
    Half4* bufD = (Half4*)(pool + 131072);    // A-lo / u-lo
    float* sRow = (float*)pool;               // row-sums, aliases bufA head

    const int n = blockIdx.x;
    const int tid = threadIdx.x;
    const float* gp = gpart + (size_t)n * npart * Q * Q;

    float4 gv[8];
    float rsum[8];
#pragma unroll
    for (int t = 0; t < 8; ++t) {
        const int idx = tid + t * 512;
        float4 v = ((const float4*)gp)[idx];
        for (int pp = 1; pp < npart; ++pp) {
            const float4 w = ((const float4*)(gp + (size_t)pp * Q * Q))[idx];
            v.x += w.x; v.y += w.y; v.z += w.z; v.w += w.w;
        }
        gv[t] = v;
        rsum[t] = fabsf(v.x) + fabsf(v.y) + fabsf(v.z) + fabsf(v.w);
    }
#pragma unroll
    for (int t = 0; t < 8; ++t) {
#pragma unroll
        for (int off = 16; off > 0; off >>= 1)
            rsum[t] += __shfl_xor(rsum[t], off);
    }
    if ((tid & 31) == 0) {
#pragma unroll
        for (int t = 0; t < 8; ++t)
            sRow[(tid >> 5) + 16 * t] = rsum[t];
    }
    __syncthreads();
    float cmax = 0.0f;
#pragma unroll
    for (int i = 0; i < 4; ++i)
        cmax = fmaxf(cmax, sRow[(tid & 31) + 32 * i]);
#pragma unroll
    for (int off = 16; off > 0; off >>= 1)
        cmax = fmaxf(cmax, __shfl_xor(cmax, off));
    __syncthreads();   // sRow reads done before bufA init overwrites alias
    const float c = cmax;
    const float rc = 1.0f / c;
    const float rs = 1.0f / sqrtf(c);

#pragma unroll
    for (int t = 0; t < 8; ++t) {
        const int idx = tid + t * 512;
        const int row = idx >> 5, c4 = idx & 31;
        const int slot = row * 32 + (c4 ^ (row & 15));
        float wv[4], zv[4];
        wv[0] = gv[t].x * rc; wv[1] = gv[t].y * rc;
        wv[2] = gv[t].z * rc; wv[3] = gv[t].w * rc;
        Half4 wh, wl, zh;
        _Float16* whp = (_Float16*)&wh;
        _Float16* wlp = (_Float16*)&wl;
        _Float16* zhp = (_Float16*)&zh;
#pragma unroll
        for (int j = 0; j < 4; ++j) {
            const _Float16 h = (_Float16)wv[j];
            whp[j] = h;
            wlp[j] = (_Float16)(wv[j] - (float)h);
            zv[j] = -0.5f * wv[j] + (((row >> 2) == c4 && (row & 3) == j) ? 1.5f : 0.0f);
            zhp[j] = (_Float16)zv[j];
        }
        bufA[slot] = wh;
        bufC[slot] = wh;
        bufD[slot] = wl;
        sZh[slot] = zh;
    }
    __syncthreads();

    const int lane = tid & 63;
    const int wid = tid >> 6;
    const int RB = wid * 16;
    const f32x4 zero4 = {0.0f, 0.0f, 0.0f, 0.0f};
    Half4* cur = bufA;
    Half4* scr = bufB;

    for (int it = 0; it < NS_LOOP; ++it) {
        f32x4 a1[8];
#pragma unroll
        for (int fj = 0; fj < 8; ++fj) a1[fj] = zero4;
#pragma unroll
        for (int kb = 0; kb < 4; ++kb) {
            const half8 af = frag_ld(cur, RB, kb * 8, lane);
#pragma unroll
            for (int fj = 0; fj < 8; ++fj) {
                const half8 bf = frag_ld(cur, fj * 16, kb * 8, lane);
                a1[fj] = __builtin_amdgcn_mfma_f32_16x16x32_f16(af, bf, a1[fj], 0, 0, 0);
            }
        }
#pragma unroll
        for (int fj = 0; fj < 8; ++fj) {
            const int p = cpos(RB, fj * 16, lane);
            cwrite(scr, p, 1.5f * cread(cur, p) - 0.5f * a1[fj]);
        }
        __syncthreads();

        f32x4 a2[8];
#pragma unroll
        for (int fj = 0; fj < 8; ++fj) a2[fj] = zero4;
#pragma unroll
        for (int kb = 0; kb < 4; ++kb) {
            const half8 af = frag_ld(scr, RB, kb * 8, lane);
#pragma unroll
            for (int fj = 0; fj < 8; ++fj) {
                const half8 bf = frag_ld(cur, fj * 16, kb * 8, lane);
                a2[fj] = __builtin_amdgcn_mfma_f32_16x16x32_f16(af, bf, a2[fj], 0, 0, 0);
            }
        }
        f32x4 wn[8];
#pragma unroll
        for (int fj = 0; fj < 8; ++fj) {
            const int p = cpos(RB, fj * 16, lane);
            wn[fj] = 1.5f * cread(scr, p) - 0.5f * a2[fj];
        }
        __syncthreads();
#pragma unroll
        for (int fj = 0; fj < 8; ++fj)
            cwrite(scr, cpos(RB, fj * 16, lane), wn[fj]);
        __syncthreads();

        f32x4 a3[8];
#pragma unroll
        for (int fj = 0; fj < 8; ++fj) a3[fj] = zero4;
#pragma unroll
        for (int kb = 0; kb < 4; ++kb) {
            const half8 af = frag_ld(scr, RB, kb * 8, lane);
#pragma unroll
            for (int fj = 0; fj < 8; ++fj) {
                const half8 bf = frag_ld(sZh, fj * 16, kb * 8, lane);
                a3[fj] = __builtin_amdgcn_mfma_f32_16x16x32_f16(af, bf, a3[fj], 0, 0, 0);
            }
        }
        f32x4 zn[8];
#pragma unroll
        for (int fj = 0; fj < 8; ++fj) {
            const int p = cpos(RB, fj * 16, lane);
            zn[fj] = 1.5f * cread(sZh, p) - 0.5f * a3[fj];
        }
        __syncthreads();
#pragma unroll
        for (int fj = 0; fj < 8; ++fj)
            cwrite(sZh, cpos(RB, fj * 16, lane), zn[fj]);
        __syncthreads();

        Half4* tmp = cur; cur = scr; scr = tmp;
    }

    // symmetrize z exactly
    {
        _Float16* zp = (_Float16*)sZh;
        for (int k = tid; k < Q * Q; k += 512) {
            const int r = k >> 7, cc = k & 127;
            if (r < cc) {
                const int i1 = (r * 32 + ((cc >> 2) ^ (r & 15))) * 4 + (cc & 3);
                const int i2 = (cc * 32 + ((r >> 2) ^ (cc & 15))) * 4 + (r & 3);
                const _Float16 av = (_Float16)(0.5f * ((float)zp[i1] + (float)zp[i2]));
                zp[i1] = av; zp[i2] = av;
            }
        }
    }
    __syncthreads();

    // racc = A*z -> cpos store = rows of (z*A)
    f32x4 racc[8];
#pragma unroll
    for (int fj = 0; fj < 8; ++fj) racc[fj] = zero4;
#pragma unroll
    for (int kb = 0; kb < 4; ++kb) {
        const half8 ah = frag_ld(bufC, RB, kb * 8, lane);
        const half8 al = frag_ld(bufD, RB, kb * 8, lane);
#pragma unroll
        for (int fj = 0; fj < 8; ++fj) {
            const half8 bz = frag_ld(sZh, fj * 16, kb * 8, lane);
            racc[fj] = __builtin_amdgcn_mfma_f32_16x16x32_f16(ah, bz, racc[fj], 0, 0, 0);
            racc[fj] = __builtin_amdgcn_mfma_f32_16x16x32_f16(al, bz, racc[fj], 0, 0, 0);
        }
    }
#pragma unroll
    for (int fj = 0; fj < 8; ++fj)
        cwrite_hl(bufA, bufB, cpos(RB, fj * 16, lane), racc[fj]);
    __syncthreads();

    // uacc = z*z -> bufC/bufD hi/lo
    f32x4 uacc[8];
#pragma unroll
    for (int fj = 0; fj < 8; ++fj) uacc[fj] = zero4;
#pragma unroll
    for (int kb = 0; kb < 4; ++kb) {
        const half8 az = frag_ld(sZh, RB, kb * 8, lane);
#pragma unroll
        for (int fj = 0; fj < 8; ++fj) {
            const half8 bz = frag_ld(sZh, fj * 16, kb * 8, lane);
            uacc[fj] = __builtin_amdgcn_mfma_f32_16x16x32_f16(az, bz, uacc[fj], 0, 0, 0);
        }
    }
#pragma unroll
    for (int fj = 0; fj < 8; ++fj)
        cwrite_hl(bufC, bufD, cpos(RB, fj * 16, lane), uacc[fj]);
    __syncthreads();

    // d = (z*A)*u ; Z_ref = rs*(1.5 z - 0.5 d)
    f32x4 dacc[8];
#pragma unroll
    for (int fj = 0; fj < 8; ++fj) dacc[fj] = zero4;
#pragma unroll
    for (int kb = 0; kb < 4; ++kb) {
        const half8 rh = frag_ld(bufA, RB, kb * 8, lane);
        const half8 rl = frag_ld(bufB, RB, kb * 8, lane);
#pragma unroll
        for (int fj = 0; fj < 8; ++fj) {
            const half8 uh = frag_ld(bufC, fj * 16, kb * 8, lane);
            const half8 ul = frag_ld(bufD, fj * 16, kb * 8, lane);
            dacc[fj] = __builtin_amdgcn_mfma_f32_16x16x32_f16(rh, uh, dacc[fj], 0, 0, 0);
            dacc[fj] = __builtin_amdgcn_mfma_f32_16x16x32_f16(rh, ul, dacc[fj], 0, 0, 0);
            dacc[fj] = __builtin_amdgcn_mfma_f32_16x16x32_f16(rl, uh, dacc[fj], 0, 0, 0);
        }
    }

    float* zo = Zg + (size_t)n * Q * Q;
    const int m0 = (lane >> 4) * 4;
    const int nn = lane & 15;
#pragma unroll
    for (int fj = 0; fj < 8; ++fj) {
        const f32x4 zq = cread(sZh, cpos(RB, fj * 16, lane));
#pragma unroll
        for (int j = 0; j < 4; ++j) {
            zo[(size_t)(RB + m0 + j) * Q + fj * 16 + nn] =
                rs * (1.5f * zq[j] - 0.5f * dacc[fj][j]);
        }
    }
}

// ---------------------------------------------------------------------------
// Kernel 3: out[n] = temp[n] @ Zg[n], fp16 MFMA; tempH fast path (r13/r14).
// ---------------------------------------------------------------------------
__global__ __launch_bounds__(512) void apply_kernel(
    const float* __restrict__ X, const float* __restrict__ G,
    const float* __restrict__ lrp, const float* __restrict__ Zg,
    const _Float16* __restrict__ tempH, int use_th,
    float* __restrict__ out)
{
    __shared__ __align__(16) unsigned char pool[65536];
    Half4* sTh = (Half4*)pool;
    Half4* sZh = (Half4*)(pool + 32768);

    const int n = blockIdx.x >> 3;
    const int p0 = (blockIdx.x & 7) * 128;
    const int tid = threadIdx.x;
    const float* zb = Zg + (size_t)n * Q * Q;
    float* ob = out + (size_t)n * P * Q + (size_t)p0 * Q;

#pragma unroll
    for (int t = 0; t < 8; ++t) {
        const int idx = tid + t * 512;
        const int row = idx >> 5, c4 = idx & 31;
        const float4 v = ((const float4*)zb)[idx];
        Half4 h;
        h.x = (_Float16)v.x; h.y = (_Float16)v.y;
        h.z = (_Float16)v.z; h.w = (_Float16)v.w;
        sZh[row * 32 + (c4 ^ (row & 15))] = h;
    }

    if (use_th) {
        const _Float16* tb = tempH + ((size_t)n * P + p0) * Q;
#pragma unroll
        for (int t = 0; t < 4; ++t) {
            const int idx = tid + t * 512;
            const int row = idx >> 4, hg = idx & 15;
            const half8 hv = ((const half8*)tb)[idx];
            Half4 h1, h2;
            h1.x = hv[0]; h1.y = hv[1]; h1.z = hv[2]; h1.w = hv[3];
            h2.x = hv[4]; h2.y = hv[5]; h2.z = hv[6]; h2.w = hv[7];
            const int rx = row & 15;
            sTh[row * 32 + ((hg * 2) ^ rx)] = h1;
            sTh[row * 32 + ((hg * 2 + 1) ^ rx)] = h2;
        }
    } else {
        const float lr = *lrp;
        const float* xb = X + (size_t)n * P * Q + (size_t)p0 * Q;
        const float* gb = G + (size_t)n * P * Q + (size_t)p0 * Q;
#pragma unroll
        for (int t = 0; t < 8; ++t) {
            const int idx = tid + t * 512;
            const int row = idx >> 5, c4 = idx & 31;
            const float4 xv = ((const float4*)xb)[idx];
            const float4 gv = ((const float4*)gb)[idx];
            Half4 h;
            h.x = (_Float16)(xv.x - lr * gv.x);
            h.y = (_Float16)(xv.y - lr * gv.y);
            h.z = (_Float16)(xv.z - lr * gv.z);
            h.w = (_Float16)(xv.w - lr * gv.w);
            sTh[row * 32 + (c4 ^ (row & 15))] = h;
        }
    }
    __syncthreads();

    const int lane = tid & 63;
    const int wid = tid >> 6;
    const int RB = wid * 16;
    const f32x4 zero4 = {0.0f, 0.0f, 0.0f, 0.0f};

    f32x4 a[8];
#pragma unroll
    for (int fj = 0; fj < 8; ++fj) a[fj] = zero4;
#pragma unroll
    for (int kb = 0; kb < 4; ++kb) {
        const half8 af = frag_ld(sTh, RB, kb * 8, lane);
#pragma unroll
        for (int fj = 0; fj < 8; ++fj) {
            const half8 bf = frag_ld(sZh, fj * 16, kb * 8, lane);
            a[fj] = __builtin_amdgcn_mfma_f32_16x16x32_f16(af, bf, a[fj], 0, 0, 0);
        }
    }

    const int m0 = (lane >> 4) * 4;
    const int nn = lane & 15;
#pragma unroll
    for (int fj = 0; fj < 8; ++fj) {
#pragma unroll
        for (int j = 0; j < 4; ++j) {
            ob[(size_t)(RB + m0 + j) * Q + fj * 16 + nn] = a[fj][j];
        }
    }
}

extern "C" void kernel_launch(void* const* d_in, const int* in_sizes, int n_in,
                              void* d_out, int out_size, void* d_ws, size_t ws_size,
                              hipStream_t stream) {
    const float* X  = (const float*)d_in[0];
    const float* G  = (const float*)d_in[1];
    const float* lr = (const float*)d_in[2];
    float* outp = (float*)d_out;

    const size_t QQ = (size_t)Q * Q;
    const size_t mat = (size_t)NBATCH * QQ;
    const size_t thHalves = (size_t)NBATCH * P * Q;

    const int npart_want = 4;
    const size_t need_np = (1 + npart_want) * mat * sizeof(float);
    const int npart = (ws_size >= need_np) ? npart_want : 1;
    const size_t need_th = need_np + thHalves * sizeof(_Float16);
    const int use_th = (npart == npart_want && ws_size >= need_th) ? 1 : 0;

    float* Zg    = (float*)d_ws;
    float* gpart = Zg + mat;
    _Float16* tempH = use_th ? (_Float16*)(gpart + (size_t)npart * mat) : (_Float16*)0;

    gram_kernel<<<NBATCH * npart, 512, 0, stream>>>(X, G, lr, gpart, npart, tempH);
    ns_kernel<<<NBATCH, 512, 0, stream>>>(gpart, npart, Zg);
    apply_kernel<<<NBATCH * 8, 512, 0, stream>>>(X, G, lr, Zg, tempH, use_th, outp);
}